// Round 24
// baseline (68.686 us; speedup 1.0000x reference)
//
#include <hip/hip_runtime.h>
#include <hip/hip_bf16.h>
#include <cstddef>

// MoE gate: B,S,D,E,K = 4,4096,2048,64,2. N = 16384 tokens.
// out layout: dispatch [N][E][K] (2,097,152 f) | combine [N][E][K] | lbl | z
namespace {
constexpr int kD = 2048;
constexpr int kE = 64;
constexpr int kN = 16384;
constexpr size_t kDispatchFloats = (size_t)kN * kE * 2;  // 2,097,152
constexpr size_t kWsplitOff = 1024;  // float offset of W-image region in ws
}

typedef short short8_t __attribute__((ext_vector_type(8)));
typedef float f32x4 __attribute__((ext_vector_type(4)));

// fp32 -> 2 UNSCALED bf16 splits: x ~= s1 + s2 (r22-proven numerics)
__device__ __forceinline__ void split2(float f, unsigned short& s1,
                                       unsigned short& s2) {
  __hip_bfloat16 h1 = __float2bfloat16(f);
  float r1 = f - __bfloat162float(h1);
  __hip_bfloat16 h2 = __float2bfloat16(r1);
  s1 = __builtin_bit_cast(unsigned short, h1);
  s2 = __builtin_bit_cast(unsigned short, h2);
}

// 8 floats (2x f32x4) -> one short8 per split (consumer-side convert)
__device__ __forceinline__ void split8_2(f32x4 a, f32x4 b, short8_t& o1,
                                         short8_t& o2) {
  unsigned short s1, s2;
#define SP(v, i, j) \
  split2((v)[i], s1, s2); o1[j] = (short)s1; o2[j] = (short)s2;
  SP(a, 0, 0) SP(a, 1, 1) SP(a, 2, 2) SP(a, 3, 3)
  SP(b, 0, 4) SP(b, 1, 5) SP(b, 2, 6) SP(b, 3, 7)
#undef SP
}

// ---------------------------------------------------------------------------
// Prep: zero ws accumulators + pre-split W (2 splits) into the swizzled LDS
// tile image (r22-proven). Tile g (= k/64, k-linear) is [2][64][64] shorts;
// [s][row][cs8*8+j] holds Wsplit_s[row][g*64 + (cs8 ^ (row&7))*8 + j].
__global__ __launch_bounds__(256)
void prep_kernel(const float* __restrict__ W, unsigned short* __restrict__ img,
                 float* __restrict__ ws) {
  const int t = blockIdx.x * 256 + threadIdx.x;  // 0..16383
  if (t < 512) ws[t] = 0.0f;
  const int g   = t >> 9;         // k-linear tile 0..31
  const int row = (t >> 3) & 63;
  const int cs8 = t & 7;
  const int co  = cs8 ^ (row & 7);
  const float* src = W + (size_t)row * kD + g * 64 + co * 8;
  const float4 v0 = *reinterpret_cast<const float4*>(src);
  const float4 v1 = *reinterpret_cast<const float4*>(src + 4);
  short8_t o1, o2;
  unsigned short s1, s2;
  split2(v0.x, s1, s2); o1[0]=(short)s1; o2[0]=(short)s2;
  split2(v0.y, s1, s2); o1[1]=(short)s1; o2[1]=(short)s2;
  split2(v0.z, s1, s2); o1[2]=(short)s1; o2[2]=(short)s2;
  split2(v0.w, s1, s2); o1[3]=(short)s1; o2[3]=(short)s2;
  split2(v1.x, s1, s2); o1[4]=(short)s1; o2[4]=(short)s2;
  split2(v1.y, s1, s2); o1[5]=(short)s1; o2[5]=(short)s2;
  split2(v1.z, s1, s2); o1[6]=(short)s1; o2[6]=(short)s2;
  split2(v1.w, s1, s2); o1[7]=(short)s1; o2[7]=(short)s2;
  unsigned short* dst = img + (size_t)g * 8192 + row * 64 + cs8 * 8;
  *reinterpret_cast<short8_t*>(dst + 0 * 4096) = o1;
  *reinterpret_cast<short8_t*>(dst + 1 * 4096) = o2;
}

// ---------------------------------------------------------------------------
// Fused logits+gate: SINGLE-barrier double-buffered pipeline, x never in LDS.
// Grid 512 = 32-token tiles; 512 thr = 8 waves (th tok-group x wc exp-half x
// kh k-half). 16 iterations x 128 k. Per iteration:
//   vmcnt(0)  -- DMA(c) + x(c) arrived (issued a full compute phase ago)
//   s_barrier -- buf^1 readers (iter c-1) all done -> safe to overwrite
//   issue DMA(c+1) -> buf^1  (4 x global_load_lds, overlaps compute below)
//   issue x(c+1) per-lane prefetch (4 x f32x4, lane-contiguous)
//   compute(c): B from LDS buf, A = split8_2 of x regs, 12 MFMAs
// W dbuf 2x32 KB (buf stride 16384 SHORTS -- r23 bug was 32768 shorts = OOB).
// lg overlays buf0 after the loop (safe: __syncthreads drains the wrapped
// final DMA before lg writes). Numerics == r22.
__global__ __launch_bounds__(512, 4)
void moe_kernel(const float* __restrict__ x,
                const unsigned short* __restrict__ wimg,
                float* __restrict__ out, float* __restrict__ ws) {
  __shared__ __attribute__((aligned(16))) unsigned char smem[65536];
  // [buf][tile-of-iter(=kh)][split][row][col16B*8]
  unsigned short (*wt)[2][2][64][64] =
      reinterpret_cast<unsigned short (*)[2][2][64][64]>(smem);
  float (*lg)[65] = reinterpret_cast<float (*)[65]>(smem);  // post-loop overlay
  __shared__ int ti0[32], ti1[32];
  __shared__ float tv0[32], tv1[32], tz2[32];

  const int tid  = threadIdx.x;
  const int lane = tid & 63;
  const int wv   = __builtin_amdgcn_readfirstlane(tid >> 6);  // 0..7
  const int th   = wv >> 2;        // token group (16 rows)
  const int wc   = (wv >> 1) & 1;  // expert half
  const int kh   = wv & 1;         // k-half within 128-k iteration
  const int tile = blockIdx.x;     // 0..511
  const int lrow = lane & 15;
  const int lk   = lane >> 4;

  // x: lane-private contiguous 8-float frags; iteration c, kstep ks:
  //   k = c*128 + kh*64 + ks*32 + lk*8, row = tile*32 + th*16 + lrow
  const float* __restrict__ xb =
      x + (size_t)(tile * 32 + th * 16 + lrow) * kD + kh * 64 + lk * 8;
  const unsigned short* __restrict__ wbase = wimg + tid * 8;
  unsigned short* wtf = reinterpret_cast<unsigned short*>(smem);

  f32x4 acc[2];
  const f32x4 z4 = {0.0f, 0.0f, 0.0f, 0.0f};
  acc[0] = z4; acc[1] = z4;

  // prefetch regs: [ks][j] statically unrolled
  f32x4 xc0, xc1, xc2, xc3, xn0, xn1, xn2, xn3;

  // prologue: DMA iter 0 -> buf 0; x iter 0 loads
  {
#pragma unroll
    for (int i = 0; i < 4; ++i)
      __builtin_amdgcn_global_load_lds(
          (const __attribute__((address_space(1))) void*)(wbase + i * 4096),
          (__attribute__((address_space(3))) void*)(wtf + i * 4096 + wv * 512),
          16, 0, 0);
    xc0 = *reinterpret_cast<const f32x4*>(xb);          // ks=0
    xc1 = *reinterpret_cast<const f32x4*>(xb + 4);
    xc2 = *reinterpret_cast<const f32x4*>(xb + 32);     // ks=1
    xc3 = *reinterpret_cast<const f32x4*>(xb + 36);
  }

#pragma unroll 2
  for (int c = 0; c < 16; ++c) {
    const int cb = c & 1;
    const int cn = (c + 1) & 15;   // wraps -> uniform issue on last iter
    // 1. everything for iter c has arrived (DMA c + x c)
    asm volatile("s_waitcnt vmcnt(0) lgkmcnt(0)" ::: "memory");
    __builtin_amdgcn_sched_barrier(0);
    __builtin_amdgcn_s_barrier();   // buf^1 readers (iter c-1) done
    __builtin_amdgcn_sched_barrier(0);
    // 2. issue DMA(c+1) -> other buf; overlaps the compute below
    {
      const unsigned short* wsrc = wbase + (size_t)(2 * cn) * 8192;
      unsigned short* dst = wtf + (cb ^ 1) * 16384;  // 16384 SHORTS = 32 KB
#pragma unroll
      for (int i = 0; i < 4; ++i)
        __builtin_amdgcn_global_load_lds(
            (const __attribute__((address_space(1))) void*)(wsrc + i * 4096),
            (__attribute__((address_space(3))) void*)(dst + i * 4096 + wv * 512),
            16, 0, 0);
    }
    // 3. issue x(c+1) per-lane prefetch
    {
      const float* p = xb + (size_t)cn * 128;
      xn0 = *reinterpret_cast<const f32x4*>(p);
      xn1 = *reinterpret_cast<const f32x4*>(p + 4);
      xn2 = *reinterpret_cast<const f32x4*>(p + 32);
      xn3 = *reinterpret_cast<const f32x4*>(p + 36);
    }
    __builtin_amdgcn_sched_barrier(0);
    // 4. compute iter c from buf cb (B in LDS, A in regs)
    __builtin_amdgcn_s_setprio(1);
#pragma unroll
    for (int ks = 0; ks < 2; ++ks) {
      const int kc = ks * 4 + lk;     // 16B col 0..7 within the kh tile
      short8_t b1[2], b2[2];
#pragma unroll
      for (int nt = 0; nt < 2; ++nt) {
        const int e = wc * 32 + nt * 16 + lrow;
        const int cw = (kc ^ (e & 7)) * 8;
        b1[nt] = *reinterpret_cast<const short8_t*>(&wt[cb][kh][0][e][cw]);
        b2[nt] = *reinterpret_cast<const short8_t*>(&wt[cb][kh][1][e][cw]);
      }
      short8_t a1, a2;
      if (ks == 0) split8_2(xc0, xc1, a1, a2);
      else         split8_2(xc2, xc3, a1, a2);
#pragma unroll
      for (int nt = 0; nt < 2; ++nt) {
        acc[nt] = __builtin_amdgcn_mfma_f32_16x16x32_bf16(a1, b1[nt], acc[nt], 0, 0, 0);
        acc[nt] = __builtin_amdgcn_mfma_f32_16x16x32_bf16(a1, b2[nt], acc[nt], 0, 0, 0);
        acc[nt] = __builtin_amdgcn_mfma_f32_16x16x32_bf16(a2, b1[nt], acc[nt], 0, 0, 0);
      }
    }
    __builtin_amdgcn_s_setprio(0);
    // rotate prefetch regs (renamed away by unroll-2)
    xc0 = xn0; xc1 = xn1; xc2 = xn2; xc3 = xn3;
  }

  // ---- kh-merge into lg[32][65] (overlays buf0; __syncthreads drains the
  // wrapped final DMA before any lg write) ----------------------------------
  __syncthreads();
  if (kh == 1) {
#pragma unroll
    for (int nt = 0; nt < 2; ++nt)
#pragma unroll
      for (int r = 0; r < 4; ++r)
        lg[th * 16 + lk * 4 + r][wc * 32 + nt * 16 + lrow] = acc[nt][r];
  }
  __syncthreads();
  if (kh == 0) {
#pragma unroll
    for (int nt = 0; nt < 2; ++nt)
#pragma unroll
      for (int r = 0; r < 4; ++r) {
        const int t = th * 16 + lk * 4 + r;
        const int e = wc * 32 + nt * 16 + lrow;
        lg[t][e] += acc[nt][r];
      }
  }
  __syncthreads();

  // ---- in-block gate: softmax + top-2 + z (32 tokens) ---------------------
  if (tid < 32) {
    float v0 = -INFINITY, v1 = -INFINITY;
    int i0 = 0, i1 = 0;
    for (int e = 0; e < kE; ++e) {
      const float l = lg[tid][e];
      if (l > v0) { v1 = v0; i1 = i0; v0 = l; i0 = e; }
      else if (l > v1) { v1 = l; i1 = e; }
    }
    const float m = v0;
    float s = 0.0f;
    for (int e = 0; e < kE; ++e) s += __expf(lg[tid][e] - m);
    const float rs = 1.0f / s;
    float zexp = 0.0f;
    for (int e = 0; e < kE; ++e) zexp += __expf(__expf(lg[tid][e] - m) * rs);
    const float z = logf(zexp);
    ti0[tid] = i0; ti1[tid] = i1;
    tv0[tid] = rs;                    // exp(v0-m)*rs with v0==m
    tv1[tid] = __expf(v1 - m) * rs;
    tz2[tid] = z * z;
  }
  __syncthreads();

  // losses: thread = expert (deterministic in-block order); z2 via wave 0
  if (tid < kE) {
    float g = 0.0f, cnt = 0.0f;
    for (int t = 0; t < 32; ++t) {
      if (ti0[t] == tid) { g += tv0[t]; cnt += 1.0f; }
      if (ti1[t] == tid) { g += tv1[t]; cnt += 1.0f; }
    }
    atomicAdd(&ws[tid], g);
    atomicAdd(&ws[kE + tid], cnt);
  }
  if (tid < 32) {
    float z2 = tz2[tid];
    z2 += __shfl_down(z2, 16);
    z2 += __shfl_down(z2, 8);
    z2 += __shfl_down(z2, 4);
    z2 += __shfl_down(z2, 2);
    z2 += __shfl_down(z2, 1);
    if (tid == 0) atomicAdd(&ws[2 * kE], z2);
  }

  // outputs: 16 threads/token, 2 float4 per tensor each, coalesced
  {
    const int t = tid >> 4, sub = tid & 15;
    const int i0 = ti0[t], i1 = ti1[t];
    const float v0 = tv0[t], v1 = tv1[t];
    const size_t n = (size_t)tile * 32 + t;
    float4* __restrict__ dp = reinterpret_cast<float4*>(out) + n * 32;
    float4* __restrict__ cp =
        reinterpret_cast<float4*>(out) + kDispatchFloats / 4 + n * 32;
#pragma unroll
    for (int j = 0; j < 2; ++j) {
      const int qq = sub * 2 + j;
      const int e0 = qq * 2, e1 = qq * 2 + 1;
      const float d0v = (e0 == i0 || e0 == i1) ? 1.0f : 0.0f;
      const float d1v = (e1 == i0 || e1 == i1) ? 1.0f : 0.0f;
      const float c0 = (e0 == i0) ? v0 : ((e0 == i1) ? v1 : 0.0f);
      const float c1 = (e1 == i0) ? v0 : ((e1 == i1) ? v1 : 0.0f);
      dp[qq] = make_float4(d0v, 0.0f, d1v, 0.0f);
      cp[qq] = make_float4(c0, 0.0f, c1, 0.0f);
    }
  }
}

// ---------------------------------------------------------------------------
__global__ void finalize_kernel(const float* __restrict__ ws,
                                float* __restrict__ out) {
  const int e = threadIdx.x;  // 64 threads
  float prod = ws[e] * ws[kE + e];
  for (int off = 32; off; off >>= 1) prod += __shfl_down(prod, off);
  if (e == 0) {
    const size_t base = kDispatchFloats * 2;
    const float invN = 1.0f / (float)kN;
    out[base]     = prod * ((float)kE * invN * invN);  // load_balancing_loss
    out[base + 1] = ws[2 * kE] * invN;                 // router_z_loss
  }
}

// ---------------------------------------------------------------------------
extern "C" void kernel_launch(void* const* d_in, const int* in_sizes, int n_in,
                              void* d_out, int out_size, void* d_ws,
                              size_t ws_size, hipStream_t stream) {
  const float* x = (const float*)d_in[0];  // [4,4096,2048] fp32
  const float* W = (const float*)d_in[1];  // [64,2048] fp32
  float* out = (float*)d_out;
  float* ws = (float*)d_ws;
  unsigned short* wimg = (unsigned short*)(ws + kWsplitOff);

  prep_kernel<<<64, 256, 0, stream>>>(W, wimg, ws);
  moe_kernel<<<512, 512, 0, stream>>>(x, wimg, out, ws);
  finalize_kernel<<<1, kE, 0, stream>>>(ws, out);
}

// Round 25
// 65.312 us; speedup vs baseline: 1.0517x; 1.0517x over previous
//
#include <hip/hip_runtime.h>
#include <hip/hip_bf16.h>
#include <cstddef>

// MoE gate: B,S,D,E,K = 4,4096,2048,64,2. N = 16384 tokens.
// out layout: dispatch [N][E][K] (2,097,152 f) | combine [N][E][K] | lbl | z
namespace {
constexpr int kD = 2048;
constexpr int kE = 64;
constexpr int kN = 16384;
constexpr size_t kDispatchFloats = (size_t)kN * kE * 2;  // 2,097,152
constexpr size_t kWsplitOff = 1024;  // float offset of W-image region in ws
}

typedef short short8_t __attribute__((ext_vector_type(8)));
typedef float f32x4 __attribute__((ext_vector_type(4)));

// fp32 -> 2 UNSCALED bf16 splits: x ~= s1 + s2 (captures ~16 mantissa bits).
__device__ __forceinline__ void split2(float f, unsigned short& s1,
                                       unsigned short& s2) {
  __hip_bfloat16 h1 = __float2bfloat16(f);
  float r1 = f - __bfloat162float(h1);
  __hip_bfloat16 h2 = __float2bfloat16(r1);
  s1 = __builtin_bit_cast(unsigned short, h1);
  s2 = __builtin_bit_cast(unsigned short, h2);
}

// 8 floats (2x f32x4) -> one short8 per split (consumer-side convert)
__device__ __forceinline__ void split8_2(f32x4 a, f32x4 b, short8_t& o1,
                                         short8_t& o2) {
  unsigned short s1, s2;
#define SP(v, i, j) \
  split2((v)[i], s1, s2); o1[j] = (short)s1; o2[j] = (short)s2;
  SP(a, 0, 0) SP(a, 1, 1) SP(a, 2, 2) SP(a, 3, 3)
  SP(b, 0, 4) SP(b, 1, 5) SP(b, 2, 6) SP(b, 3, 7)
#undef SP
}

// ---------------------------------------------------------------------------
// Prep: zero ws accumulators + pre-split W (2 splits) into the swizzled LDS
// tile image. Tile g (= k/64, k-linear) is [2][64][64] shorts (16 KB);
// [s][row][cs8*8+j] holds Wsplit_s[row][g*64 + (cs8 ^ (row&7))*8 + j] so a
// linear global_load_lds DMA reproduces the swizzled tile verbatim.
__global__ __launch_bounds__(256)
void prep_kernel(const float* __restrict__ W, unsigned short* __restrict__ img,
                 float* __restrict__ ws) {
  const int t = blockIdx.x * 256 + threadIdx.x;  // 0..16383
  if (t < 512) ws[t] = 0.0f;
  const int g   = t >> 9;         // k-linear tile 0..31
  const int row = (t >> 3) & 63;
  const int cs8 = t & 7;
  const int co  = cs8 ^ (row & 7);
  const float* src = W + (size_t)row * kD + g * 64 + co * 8;
  const float4 v0 = *reinterpret_cast<const float4*>(src);
  const float4 v1 = *reinterpret_cast<const float4*>(src + 4);
  short8_t o1, o2;
  unsigned short s1, s2;
  split2(v0.x, s1, s2); o1[0]=(short)s1; o2[0]=(short)s2;
  split2(v0.y, s1, s2); o1[1]=(short)s1; o2[1]=(short)s2;
  split2(v0.z, s1, s2); o1[2]=(short)s1; o2[2]=(short)s2;
  split2(v0.w, s1, s2); o1[3]=(short)s1; o2[3]=(short)s2;
  split2(v1.x, s1, s2); o1[4]=(short)s1; o2[4]=(short)s2;
  split2(v1.y, s1, s2); o1[5]=(short)s1; o2[5]=(short)s2;
  split2(v1.z, s1, s2); o1[6]=(short)s1; o2[6]=(short)s2;
  split2(v1.w, s1, s2); o1[7]=(short)s1; o2[7]=(short)s2;
  unsigned short* dst = img + (size_t)g * 8192 + row * 64 + cs8 * 8;
  *reinterpret_cast<short8_t*>(dst + 0 * 4096) = o1;
  *reinterpret_cast<short8_t*>(dst + 1 * 4096) = o2;
}

// ---------------------------------------------------------------------------
// Fused logits+gate (r22 structure -- measured best, 65.7 us).
// Grid 512 = 32-token tiles; 512 thr = 8 waves (th tok-group x wc exp-half x
// kh k-half). 16 iterations x 128 k: x raw fp32 [32][128] swizzled (16 KB),
// W = 2 k-linear image tiles DMA'd (32 KB). 48 KB LDS -> 3 blocks/CU.
__global__ __launch_bounds__(512, 6)
void moe_kernel(const float* __restrict__ x,
                const unsigned short* __restrict__ wimg,
                float* __restrict__ out, float* __restrict__ ws) {
  __shared__ __attribute__((aligned(16))) unsigned char smem[49152];
  float* xsf = reinterpret_cast<float*>(smem);  // [32][128] raw x (16 KB)
  unsigned short (*wt)[2][64][64] =
      reinterpret_cast<unsigned short (*)[2][64][64]>(smem + 16384);  // 2x16KB
  float (*lg)[65] = reinterpret_cast<float (*)[65]>(smem);  // reuse x region
  __shared__ int ti0[32], ti1[32];
  __shared__ float tv0[32], tv1[32], tz2[32];

  const int tid  = threadIdx.x;
  const int lane = tid & 63;
  const int wv   = __builtin_amdgcn_readfirstlane(tid >> 6);  // 0..7
  const int th   = wv >> 2;        // token group (16 rows)
  const int wc   = (wv >> 1) & 1;  // expert half
  const int kh   = wv & 1;         // k-half within 128-k iteration
  const int tile = blockIdx.x;     // 0..511
  const int lrow = lane & 15;
  const int lk   = lane >> 4;

  // staging role: 16 threads per token row, 8 contiguous floats each
  const int row = tid >> 4, t16 = tid & 15;
  const float4* __restrict__ bx = reinterpret_cast<const float4*>(x) +
      ((size_t)tile * 32 + row) * 512 + t16 * 2;
  const unsigned short* __restrict__ wbase = wimg + tid * 8;
  unsigned short* wtf = &wt[0][0][0][0];
  const int su0 = ((2 * t16) ^ (row & 31)) * 4;      // swizzled float offsets
  const int su1 = ((2 * t16 + 1) ^ (row & 31)) * 4;

  f32x4 acc[2];
  const f32x4 z4 = {0.0f, 0.0f, 0.0f, 0.0f};
  acc[0] = z4; acc[1] = z4;

  float4 vx0 = bx[0], vx1 = bx[1];

  for (int c = 0; c < 16; ++c) {
    // 1. W DMA: 2 k-linear tiles (g = 2c, 2c+1), 4 x 16B/thread (32 KB)
    const unsigned short* wsrc = wbase + (size_t)(2 * c) * 8192;
#pragma unroll
    for (int i = 0; i < 4; ++i)
      __builtin_amdgcn_global_load_lds(
          (const __attribute__((address_space(1))) void*)(wsrc + i * 4096),
          (__attribute__((address_space(3))) void*)(wtf + i * 4096 + wv * 512),
          16, 0, 0);
    __builtin_amdgcn_sched_barrier(0);  // pin: x-loads issue AFTER DMAs
    // 2. consume x(c) regs; issue x(c+1) prefetch (wraps -> uniform vmcnt)
    const float4 xa = vx0, xb = vx1;
    const int cn = (c + 1) & 15;
    vx0 = bx[cn * 32 + 0];
    vx1 = bx[cn * 32 + 1];
    // 3. RAW swizzled LDS store of x(c)
    *reinterpret_cast<float4*>(xsf + row * 128 + su0) = xa;
    *reinterpret_cast<float4*>(xsf + row * 128 + su1) = xb;
    // 4. W-DMA + ds_writes drained; x(c+1) (2 loads) stays in flight
    asm volatile("s_waitcnt vmcnt(2) lgkmcnt(0)" ::: "memory");
    __builtin_amdgcn_sched_barrier(0);
    __builtin_amdgcn_s_barrier();
    __builtin_amdgcn_sched_barrier(0);
    // 5. MFMA: this wave's 64-k half (wt[kh]); 2 ks x 2 nt x 3 products
    __builtin_amdgcn_s_setprio(1);
#pragma unroll
    for (int ks = 0; ks < 2; ++ks) {
      const int kc = ks * 4 + lk;     // 0..7 within wt[kh]
      short8_t b1[2], b2[2];
#pragma unroll
      for (int nt = 0; nt < 2; ++nt) {
        const int e = wc * 32 + nt * 16 + lrow;
        const int cw = (kc ^ (e & 7)) * 8;
        b1[nt] = *reinterpret_cast<const short8_t*>(&wt[kh][0][e][cw]);
        b2[nt] = *reinterpret_cast<const short8_t*>(&wt[kh][1][e][cw]);
      }
      const int ra = th * 16 + lrow;
      const int u0 = kh * 16 + ks * 8 + 2 * lk;  // 16B unit within 128-k row
      const int ca0 = ((u0) ^ (ra & 31)) * 4;
      const int ca1 = ((u0 + 1) ^ (ra & 31)) * 4;
      const f32x4 va = *reinterpret_cast<const f32x4*>(xsf + ra * 128 + ca0);
      const f32x4 vb = *reinterpret_cast<const f32x4*>(xsf + ra * 128 + ca1);
      short8_t a1, a2;
      split8_2(va, vb, a1, a2);
#pragma unroll
      for (int nt = 0; nt < 2; ++nt) {
        acc[nt] = __builtin_amdgcn_mfma_f32_16x16x32_bf16(a1, b1[nt], acc[nt], 0, 0, 0);
        acc[nt] = __builtin_amdgcn_mfma_f32_16x16x32_bf16(a1, b2[nt], acc[nt], 0, 0, 0);
        acc[nt] = __builtin_amdgcn_mfma_f32_16x16x32_bf16(a2, b1[nt], acc[nt], 0, 0, 0);
      }
    }
    __builtin_amdgcn_s_setprio(0);
    __builtin_amdgcn_sched_barrier(0);
    __builtin_amdgcn_s_barrier();  // all reads of this iteration done
  }

  // ---- kh-merge into lg[32][65] (reuses x region; K loop fully done) ------
  if (kh == 1) {
#pragma unroll
    for (int nt = 0; nt < 2; ++nt)
#pragma unroll
      for (int r = 0; r < 4; ++r)
        lg[th * 16 + lk * 4 + r][wc * 32 + nt * 16 + lrow] = acc[nt][r];
  }
  __syncthreads();
  if (kh == 0) {
#pragma unroll
    for (int nt = 0; nt < 2; ++nt)
#pragma unroll
      for (int r = 0; r < 4; ++r) {
        const int t = th * 16 + lk * 4 + r;
        const int e = wc * 32 + nt * 16 + lrow;
        lg[t][e] += acc[nt][r];
      }
  }
  __syncthreads();

  // ---- in-block gate: softmax + top-2 + z (32 tokens) ---------------------
  if (tid < 32) {
    float v0 = -INFINITY, v1 = -INFINITY;
    int i0 = 0, i1 = 0;
    for (int e = 0; e < kE; ++e) {
      const float l = lg[tid][e];
      if (l > v0) { v1 = v0; i1 = i0; v0 = l; i0 = e; }
      else if (l > v1) { v1 = l; i1 = e; }
    }
    const float m = v0;
    float s = 0.0f;
    for (int e = 0; e < kE; ++e) s += __expf(lg[tid][e] - m);
    const float rs = 1.0f / s;
    float zexp = 0.0f;
    for (int e = 0; e < kE; ++e) zexp += __expf(__expf(lg[tid][e] - m) * rs);
    const float z = logf(zexp);
    ti0[tid] = i0; ti1[tid] = i1;
    tv0[tid] = rs;                    // exp(v0-m)*rs with v0==m
    tv1[tid] = __expf(v1 - m) * rs;
    tz2[tid] = z * z;
  }
  __syncthreads();

  // losses: thread = expert (deterministic in-block order); z2 via wave 0
  if (tid < kE) {
    float g = 0.0f, cnt = 0.0f;
    for (int t = 0; t < 32; ++t) {
      if (ti0[t] == tid) { g += tv0[t]; cnt += 1.0f; }
      if (ti1[t] == tid) { g += tv1[t]; cnt += 1.0f; }
    }
    atomicAdd(&ws[tid], g);
    atomicAdd(&ws[kE + tid], cnt);
  }
  if (tid < 32) {
    float z2 = tz2[tid];
    z2 += __shfl_down(z2, 16);
    z2 += __shfl_down(z2, 8);
    z2 += __shfl_down(z2, 4);
    z2 += __shfl_down(z2, 2);
    z2 += __shfl_down(z2, 1);
    if (tid == 0) atomicAdd(&ws[2 * kE], z2);
  }

  // outputs: 16 threads/token, 2 float4 per tensor each, coalesced
  {
    const int t = tid >> 4, sub = tid & 15;
    const int i0 = ti0[t], i1 = ti1[t];
    const float v0 = tv0[t], v1 = tv1[t];
    const size_t n = (size_t)tile * 32 + t;
    float4* __restrict__ dp = reinterpret_cast<float4*>(out) + n * 32;
    float4* __restrict__ cp =
        reinterpret_cast<float4*>(out) + kDispatchFloats / 4 + n * 32;
#pragma unroll
    for (int j = 0; j < 2; ++j) {
      const int qq = sub * 2 + j;
      const int e0 = qq * 2, e1 = qq * 2 + 1;
      const float d0v = (e0 == i0 || e0 == i1) ? 1.0f : 0.0f;
      const float d1v = (e1 == i0 || e1 == i1) ? 1.0f : 0.0f;
      const float c0 = (e0 == i0) ? v0 : ((e0 == i1) ? v1 : 0.0f);
      const float c1 = (e1 == i0) ? v0 : ((e1 == i1) ? v1 : 0.0f);
      dp[qq] = make_float4(d0v, 0.0f, d1v, 0.0f);
      cp[qq] = make_float4(c0, 0.0f, c1, 0.0f);
    }
  }
}

// ---------------------------------------------------------------------------
__global__ void finalize_kernel(const float* __restrict__ ws,
                                float* __restrict__ out) {
  const int e = threadIdx.x;  // 64 threads
  float prod = ws[e] * ws[kE + e];
  for (int off = 32; off; off >>= 1) prod += __shfl_down(prod, off);
  if (e == 0) {
    const size_t base = kDispatchFloats * 2;
    const float invN = 1.0f / (float)kN;
    out[base]     = prod * ((float)kE * invN * invN);  // load_balancing_loss
    out[base + 1] = ws[2 * kE] * invN;                 // router_z_loss
  }
}

// ---------------------------------------------------------------------------
extern "C" void kernel_launch(void* const* d_in, const int* in_sizes, int n_in,
                              void* d_out, int out_size, void* d_ws,
                              size_t ws_size, hipStream_t stream) {
  const float* x = (const float*)d_in[0];  // [4,4096,2048] fp32
  const float* W = (const float*)d_in[1];  // [64,2048] fp32
  float* out = (float*)d_out;
  float* ws = (float*)d_ws;
  unsigned short* wimg = (unsigned short*)(ws + kWsplitOff);

  prep_kernel<<<64, 256, 0, stream>>>(W, wimg, ws);
  moe_kernel<<<512, 512, 0, stream>>>(x, wimg, out, ws);
  finalize_kernel<<<1, kE, 0, stream>>>(ws, out);
}